// Round 9
// baseline (140.438 us; speedup 1.0000x reference)
//
#include <hip/hip_runtime.h>
#include <math.h>

// ---------------------------------------------------------------------------
// H=8, D=256, DH=32, SH=64, B=4, L_LEFT=128, L_RIGHT=256, BH=32.
// Output: concat(out_l [4,128,256], out_r [4,256,256]) = 393216 f32.
//
// Algebra: tanh(x)=1-2/(1+e^{2x}); softmax shift-invariance drops Sum(wv);
// e^{2(qf+kf)}=e^{2qf}*e^{2kf}.  K1 stores Ek=e^{2kf} (k-contig).  K2 computes
// its block's Eq tile in-kernel (LDS), then wave-local scores
// s~ = Sum_h wv_h/(1+Eq*Ek) with h-paired reciprocals, softmax in registers,
// P in LDS, PV, cross-kc reduce.
// Phase A is hc-outermost (eq/wv loads hoisted out of j); all register-array
// indexing fully static (R6 lesson: dynamic component select -> scratch).
// ---------------------------------------------------------------------------

#define LOG2E 1.4426950408889634f
#define SCALE2 (2.0f * LOG2E)
#define NEGS  (-2.0f * LOG2E)

// workspace offsets (floats)
#define OFF_EKL 0          // [32][64][256]  k-contig (transposed)
#define OFF_EKR 524288     // [32][64][128]
#define OFF_HOL 786432     // [4][128][256]
#define OFF_HOR 917504     // [4][256][256]

static __device__ __forceinline__ float fast_exp2(float x) {
#if __has_builtin(__builtin_amdgcn_exp2f)
    return __builtin_amdgcn_exp2f(x);
#else
    return exp2f(x);
#endif
}
static __device__ __forceinline__ float fast_rcp(float x) {
#if __has_builtin(__builtin_amdgcn_rcpf)
    return __builtin_amdgcn_rcpf(x);
#else
    return 1.0f / x;
#endif
}

// ---------------------------------------------------------------------------
// K1: K-side feature projections + exp2, stored [bh][h][l] (transposed
// through LDS).  grid 768 x 256: [0,512) kr->EKL (L=256), [512,768) kl->EKR.
// ---------------------------------------------------------------------------
__global__ __launch_bounds__(256) void k1_proj(
    const float* __restrict__ kr, const float* __restrict__ kl,
    const float* __restrict__ wkl, const float* __restrict__ wkr,
    float* __restrict__ ws)
{
    __shared__ float tlds[64 * 17];
    int blk = blockIdx.x;
    const float* X; const float* W; float* out; int L;
    if (blk < 512) { X = kr; W = wkl; out = ws + OFF_EKL; L = 256; }
    else           { X = kl; W = wkr; out = ws + OFF_EKR; L = 128; blk -= 512; }

    const int tiles = L >> 4;
    const int bh = blk / tiles;
    const int l0 = (blk - bh * tiles) << 4;
    const int b = bh >> 3, hd = bh & 7;
    const int t = threadIdx.x;
    const int h = t & 63, lsub = t >> 6;

    float wcol[32];
#pragma unroll
    for (int j = 0; j < 32; ++j) wcol[j] = W[j * 64 + h];

    const float* xb = X + ((b * L + l0 + lsub * 4) * 256) + hd * 32;

#pragma unroll
    for (int i = 0; i < 4; ++i) {
        const float4* xp = (const float4*)(xb + i * 256);
        float acc = 0.f;
#pragma unroll
        for (int j4 = 0; j4 < 8; ++j4) {
            float4 a = xp[j4];
            acc += a.x * wcol[4 * j4 + 0];
            acc += a.y * wcol[4 * j4 + 1];
            acc += a.z * wcol[4 * j4 + 2];
            acc += a.w * wcol[4 * j4 + 3];
        }
        tlds[h * 17 + lsub * 4 + i] = fast_exp2(acc * SCALE2);
    }
    __syncthreads();
    const int ll = t & 15, hq = t >> 4;
#pragma unroll
    for (int hh = 0; hh < 4; ++hh) {
        const int h2 = hq + 16 * hh;
        out[bh * (64 * L) + h2 * L + l0 + ll] = tlds[h2 * 17 + ll];
    }
}

// ---------------------------------------------------------------------------
// K2 fused: Eq preamble (LDS) -> wave-local scores+softmax -> P in LDS ->
// PV -> reduce.  grid 1024 x 256: [0,512) left (LK=256, TQ=8),
// [512,1024) right (LK=128, TQ=16).
// ---------------------------------------------------------------------------
template<int LK, int LQ, int TQ>
static __device__ __forceinline__ void attn_fused(
    int bh, int q0,
    const float* __restrict__ xq, const float* __restrict__ wq,
    const float* __restrict__ ek,
    const float* __restrict__ wv, const float* __restrict__ v,
    int valid, float* __restrict__ ho,
    float* P_lds, float* pv_lds, float* eq_lds)
{
    constexpr int RPT = TQ / 4;     // q-rows per wave (4 waves)
    constexpr int J   = LK / 64;    // k-columns per lane
    constexpr int CS  = LK / 8;     // k-slice per kc-group in PV
    const int t = threadIdx.x;
    const int lane = t & 63, w = t >> 6;
    const int b = bh >> 3, hd = bh & 7;

    // ---- Eq preamble: TQ x 64 tile into LDS ------------------------------
    {
        const int h = lane;
        float wcol[32];
#pragma unroll
        for (int j = 0; j < 32; ++j) wcol[j] = wq[j * 64 + h];
#pragma unroll
        for (int i = 0; i < TQ / 4; ++i) {
            const int r = w + 4 * i;
            const float4* xp = (const float4*)(xq + (b * LQ + q0 + r) * 256 + hd * 32);
            float acc = 0.f;
#pragma unroll
            for (int j4 = 0; j4 < 8; ++j4) {
                float4 a = xp[j4];
                acc += a.x * wcol[4 * j4 + 0];
                acc += a.y * wcol[4 * j4 + 1];
                acc += a.z * wcol[4 * j4 + 2];
                acc += a.w * wcol[4 * j4 + 3];
            }
            eq_lds[r * 64 + h] = fast_exp2(acc * SCALE2);
        }
    }
    __syncthreads();

    // ---- scores + softmax (registers + shuffles only) --------------------
    {
        const int row0 = w * RPT;
        float acc[RPT][J];
#pragma unroll
        for (int r = 0; r < RPT; ++r)
#pragma unroll
            for (int j = 0; j < J; ++j) acc[r][j] = 0.f;

        const float* ekb = ek + bh * (64 * LK) + lane;

        bool live[J];
#pragma unroll
        for (int j = 0; j < J; ++j) live[j] = (64 * j < valid);   // wave-uniform

#pragma unroll
        for (int hc = 0; hc < 16; ++hc) {
            const float4 wv4 = *(const float4*)(wv + hc * 4);     // uniform
            float wva[4] = {wv4.x, wv4.y, wv4.z, wv4.w};
            float eqa[RPT][4];
#pragma unroll
            for (int r = 0; r < RPT; ++r) {
                const float4 q4 = *(const float4*)(eq_lds + (row0 + r) * 64 + hc * 4);
                eqa[r][0] = q4.x; eqa[r][1] = q4.y;
                eqa[r][2] = q4.z; eqa[r][3] = q4.w;
            }
#pragma unroll
            for (int hp = 0; hp < 2; ++hp) {
                const float* ekp0 = ekb + (hc * 4 + 2 * hp) * LK;
#pragma unroll
                for (int j = 0; j < J; ++j) {
                    if (live[j]) {                    // wave-uniform branch
                        const float ek0 = ekp0[64 * j];
                        const float ek1 = ekp0[LK + 64 * j];
#pragma unroll
                        for (int r = 0; r < RPT; ++r) {
                            const float da = fmaf(eqa[r][2 * hp    ], ek0, 1.0f);
                            const float db = fmaf(eqa[r][2 * hp + 1], ek1, 1.0f);
                            float n = wva[2 * hp] * db;
                            n = fmaf(wva[2 * hp + 1], da, n);
                            acc[r][j] = fmaf(n, fast_rcp(da * db), acc[r][j]);
                        }
                    }
                }
            }
        }

#pragma unroll
        for (int r = 0; r < RPT; ++r) {
            float sv[J];
            float m = -3.0e38f;
#pragma unroll
            for (int j = 0; j < J; ++j) {
                sv[j] = (64 * j + lane < valid) ? acc[r][j] * NEGS : -1.0e6f;
                m = fmaxf(m, sv[j]);
            }
#pragma unroll
            for (int off = 1; off < 64; off <<= 1) m = fmaxf(m, __shfl_xor(m, off));
            float lsum = 0.f;
#pragma unroll
            for (int j = 0; j < J; ++j) { sv[j] = fast_exp2(sv[j] - m); lsum += sv[j]; }
#pragma unroll
            for (int off = 1; off < 64; off <<= 1) lsum += __shfl_xor(lsum, off);
            const float inv = fast_rcp(lsum);
#pragma unroll
            for (int j = 0; j < J; ++j)
                P_lds[(row0 + r) * LK + 64 * j + lane] = sv[j] * inv;
        }
    }
    __syncthreads();

    // ---- PV: thread = (d=t&31, kc=t>>5); V in reg chunks of 8 ------------
    {
        const int d = t & 31, kc = t >> 5;
        float acc2[TQ];
#pragma unroll
        for (int row = 0; row < TQ; ++row) acc2[row] = 0.f;

        if (kc * CS < valid) {
            const float* vp = v + (b * LK + kc * CS) * 256 + hd * 32 + d;
#pragma unroll
            for (int c = 0; c < CS / 8; ++c) {
                float vv[8];
#pragma unroll
                for (int i = 0; i < 8; ++i) vv[i] = vp[(c * 8 + i) * 256];
#pragma unroll
                for (int row = 0; row < TQ; ++row) {
                    const float4* pp = (const float4*)(P_lds + row * LK + kc * CS + c * 8);
                    const float4 p0 = pp[0], p1 = pp[1];
                    acc2[row] += p0.x * vv[0] + p0.y * vv[1] + p0.z * vv[2] + p0.w * vv[3]
                               + p1.x * vv[4] + p1.y * vv[5] + p1.z * vv[6] + p1.w * vv[7];
                }
            }
        }
#pragma unroll
        for (int row = 0; row < TQ; ++row)
            pv_lds[(kc * TQ + row) * 32 + d] = acc2[row];
    }
    __syncthreads();

    // ---- cross-kc reduce + write merged-head layout ----------------------
#pragma unroll
    for (int rr = 0; rr < (TQ * 32) / 256; ++rr) {
        const int idx = t + 256 * rr;
        const int dd = idx & 31, row = idx >> 5;
        float o = 0.f;
#pragma unroll
        for (int kc2 = 0; kc2 < 8; ++kc2) o += pv_lds[(kc2 * TQ + row) * 32 + dd];
        ho[(b * LQ + q0 + row) * 256 + hd * 32 + dd] = o;
    }
}

__global__ __launch_bounds__(256, 6) void k2_attn(
    const float* __restrict__ ql, const float* __restrict__ qr,
    const float* __restrict__ wql, const float* __restrict__ wqr,
    const float* __restrict__ ekl, const float* __restrict__ ekr,
    const float* __restrict__ wvl, const float* __restrict__ wvr,
    const float* __restrict__ vr, const float* __restrict__ vl,
    const int* __restrict__ vlr, const int* __restrict__ vll,
    float* __restrict__ hol, float* __restrict__ hor)
{
    __shared__ __align__(16) float P_lds[2048];    // 8 KB (8x256 / 16x128)
    __shared__ __align__(16) float pv_lds[4096];   // 16 KB
    __shared__ __align__(16) float eq_lds[1024];   // 4 KB (TQ x 64, max TQ=16)
    int blk = blockIdx.x;
    if (blk < 512) {            // left: LK=256, LQ=128, TQ=8
        const int bh = blk >> 4, q0 = (blk & 15) << 3;
        attn_fused<256, 128, 8>(bh, q0, ql, wql, ekl, wvl, vr, vlr[bh >> 3],
                                hol, P_lds, pv_lds, eq_lds);
    } else {                    // right: LK=128, LQ=256, TQ=16
        blk -= 512;
        const int bh = blk >> 4, q0 = (blk & 15) << 4;
        attn_fused<128, 256, 16>(bh, q0, qr, wqr, ekr, wvr, vl, vll[bh >> 3],
                                 hor, P_lds, pv_lds, eq_lds);
    }
}

// ---------------------------------------------------------------------------
// K3: output projections.  4 rows/block -> 384 blocks.
// ---------------------------------------------------------------------------
__global__ __launch_bounds__(256) void k3_proj(
    const float* __restrict__ ws,
    const float* __restrict__ wol, const float* __restrict__ wor,
    float* __restrict__ out)
{
    __shared__ __align__(16) float a_lds[1024];
    const int row0 = blockIdx.x * 4;
    const float* A; const float* W; float* op; int lr0;
    if (row0 < 512) { A = ws + OFF_HOL; W = wol; op = out;          lr0 = row0; }
    else            { A = ws + OFF_HOR; W = wor; op = out + 131072; lr0 = row0 - 512; }

    const int t = threadIdx.x;
#pragma unroll
    for (int i = 0; i < 4; ++i) a_lds[i * 256 + t] = A[(lr0 + i) * 256 + t];
    __syncthreads();

    float acc[4];
#pragma unroll
    for (int r = 0; r < 4; ++r) acc[r] = 0.f;

#pragma unroll 4
    for (int k4 = 0; k4 < 64; ++k4) {
        const float w0 = W[(k4 * 4 + 0) * 256 + t];
        const float w1 = W[(k4 * 4 + 1) * 256 + t];
        const float w2 = W[(k4 * 4 + 2) * 256 + t];
        const float w3 = W[(k4 * 4 + 3) * 256 + t];
#pragma unroll
        for (int r = 0; r < 4; ++r) {
            const float4 a = *(const float4*)(a_lds + r * 256 + k4 * 4);
            acc[r] += a.x * w0 + a.y * w1 + a.z * w2 + a.w * w3;
        }
    }
#pragma unroll
    for (int r = 0; r < 4; ++r) op[(lr0 + r) * 256 + t] = acc[r];
}

// ---------------------------------------------------------------------------
extern "C" void kernel_launch(void* const* d_in, const int* in_sizes, int n_in,
                              void* d_out, int out_size, void* d_ws, size_t ws_size,
                              hipStream_t stream)
{
    const float* ql  = (const float*)d_in[0];
    const float* kr  = (const float*)d_in[1];
    const float* vr  = (const float*)d_in[2];
    const float* qr  = (const float*)d_in[3];
    const float* kl  = (const float*)d_in[4];
    const float* vl  = (const float*)d_in[5];
    const float* wql = (const float*)d_in[6];
    const float* wkl = (const float*)d_in[7];
    const float* wvl = (const float*)d_in[8];
    const float* wol = (const float*)d_in[9];
    const float* wqr = (const float*)d_in[10];
    const float* wkr = (const float*)d_in[11];
    const float* wvr = (const float*)d_in[12];
    const float* wor = (const float*)d_in[13];
    const int*   vlr = (const int*)d_in[14];
    const int*   vll = (const int*)d_in[15];
    float* ws  = (float*)d_ws;
    float* out = (float*)d_out;

    hipLaunchKernelGGL(k1_proj, dim3(768), dim3(256), 0, stream,
                       kr, kl, wkl, wkr, ws);
    hipLaunchKernelGGL(k2_attn, dim3(1024), dim3(256), 0, stream,
                       ql, qr, wql, wqr, ws + OFF_EKL, ws + OFF_EKR,
                       wvl, wvr, vr, vl, vlr, vll,
                       ws + OFF_HOL, ws + OFF_HOR);
    hipLaunchKernelGGL(k3_proj, dim3(384), dim3(256), 0, stream,
                       ws, wol, wor, out);
}

// Round 10
// 120.635 us; speedup vs baseline: 1.1642x; 1.1642x over previous
//
#include <hip/hip_runtime.h>
#include <math.h>

// ---------------------------------------------------------------------------
// H=8, D=256, DH=32, SH=64, B=4, L_LEFT=128, L_RIGHT=256, BH=32.
// Output: concat(out_l [4,128,256], out_r [4,256,256]) = 393216 f32.
//
// Algebra: tanh(x)=1-2/(1+e^{2x}); softmax shift-invariance drops Sum(wv);
// e^{2(qf+kf)}=e^{2qf}*e^{2kf}.  K1 stores Ek=e^{2kf} (k-contig).  K2 computes
// its block's Eq tile in-kernel (LDS), then wave-local scores
// s~ = Sum_h wv_h/(1+Eq*Ek) with h-paired reciprocals, softmax in registers,
// P in LDS, PV, cross-kc reduce.
// Loop-structure lessons (R6/R9): j-outermost with straight-line hc body is
// the local optimum; j-innermost spills (R6), per-j branches in the inner
// loop serialize (R9).
// ---------------------------------------------------------------------------

#define LOG2E 1.4426950408889634f
#define SCALE2 (2.0f * LOG2E)
#define NEGS  (-2.0f * LOG2E)

// workspace offsets (floats)
#define OFF_EKL 0          // [32][64][256]  k-contig (transposed)
#define OFF_EKR 524288     // [32][64][128]
#define OFF_HOL 786432     // [4][128][256]
#define OFF_HOR 917504     // [4][256][256]

static __device__ __forceinline__ float fast_exp2(float x) {
#if __has_builtin(__builtin_amdgcn_exp2f)
    return __builtin_amdgcn_exp2f(x);
#else
    return exp2f(x);
#endif
}
static __device__ __forceinline__ float fast_rcp(float x) {
#if __has_builtin(__builtin_amdgcn_rcpf)
    return __builtin_amdgcn_rcpf(x);
#else
    return 1.0f / x;
#endif
}

// ---------------------------------------------------------------------------
// K1: K-side feature projections + exp2, stored [bh][h][l] (transposed
// through LDS).  grid 768 x 256: [0,512) kr->EKL (L=256), [512,768) kl->EKR.
// ---------------------------------------------------------------------------
__global__ __launch_bounds__(256) void k1_proj(
    const float* __restrict__ kr, const float* __restrict__ kl,
    const float* __restrict__ wkl, const float* __restrict__ wkr,
    float* __restrict__ ws)
{
    __shared__ float tlds[64 * 17];
    int blk = blockIdx.x;
    const float* X; const float* W; float* out; int L;
    if (blk < 512) { X = kr; W = wkl; out = ws + OFF_EKL; L = 256; }
    else           { X = kl; W = wkr; out = ws + OFF_EKR; L = 128; blk -= 512; }

    const int tiles = L >> 4;
    const int bh = blk / tiles;
    const int l0 = (blk - bh * tiles) << 4;
    const int b = bh >> 3, hd = bh & 7;
    const int t = threadIdx.x;
    const int h = t & 63, lsub = t >> 6;

    float wcol[32];
#pragma unroll
    for (int j = 0; j < 32; ++j) wcol[j] = W[j * 64 + h];

    const float* xb = X + ((b * L + l0 + lsub * 4) * 256) + hd * 32;

#pragma unroll
    for (int i = 0; i < 4; ++i) {
        const float4* xp = (const float4*)(xb + i * 256);
        float acc = 0.f;
#pragma unroll
        for (int j4 = 0; j4 < 8; ++j4) {
            float4 a = xp[j4];
            acc += a.x * wcol[4 * j4 + 0];
            acc += a.y * wcol[4 * j4 + 1];
            acc += a.z * wcol[4 * j4 + 2];
            acc += a.w * wcol[4 * j4 + 3];
        }
        tlds[h * 17 + lsub * 4 + i] = fast_exp2(acc * SCALE2);
    }
    __syncthreads();
    const int ll = t & 15, hq = t >> 4;
#pragma unroll
    for (int hh = 0; hh < 4; ++hh) {
        const int h2 = hq + 16 * hh;
        out[bh * (64 * L) + h2 * L + l0 + ll] = tlds[h2 * 17 + ll];
    }
}

// ---------------------------------------------------------------------------
// K2 fused: Eq preamble (LDS) -> wave-local scores+softmax -> P in LDS ->
// PV -> reduce.  grid 1024 x 256: [0,512) left (LK=256, TQ=8),
// [512,1024) right (LK=128, TQ=16).
// ---------------------------------------------------------------------------
template<int LK, int LQ, int TQ>
static __device__ __forceinline__ void attn_fused(
    int bh, int q0,
    const float* __restrict__ xq, const float* __restrict__ wq,
    const float* __restrict__ ek,
    const float* __restrict__ wv, const float* __restrict__ v,
    int valid, float* __restrict__ ho,
    float* P_lds, float* pv_lds, float* eq_lds)
{
    constexpr int RPT = TQ / 4;     // q-rows per wave (4 waves)
    constexpr int J   = LK / 64;    // k-columns per lane
    constexpr int CS  = LK / 8;     // k-slice per kc-group in PV
    const int t = threadIdx.x;
    const int lane = t & 63, w = t >> 6;
    const int b = bh >> 3, hd = bh & 7;

    // ---- Eq preamble: TQ x 64 tile into LDS ------------------------------
    {
        const int h = lane;
        float wcol[32];
#pragma unroll
        for (int j = 0; j < 32; ++j) wcol[j] = wq[j * 64 + h];
#pragma unroll
        for (int i = 0; i < TQ / 4; ++i) {
            const int r = w + 4 * i;
            const float4* xp = (const float4*)(xq + (b * LQ + q0 + r) * 256 + hd * 32);
            float acc = 0.f;
#pragma unroll
            for (int j4 = 0; j4 < 8; ++j4) {
                float4 a = xp[j4];
                acc += a.x * wcol[4 * j4 + 0];
                acc += a.y * wcol[4 * j4 + 1];
                acc += a.z * wcol[4 * j4 + 2];
                acc += a.w * wcol[4 * j4 + 3];
            }
            eq_lds[r * 64 + h] = fast_exp2(acc * SCALE2);
        }
    }
    __syncthreads();

    // ---- scores + softmax (registers + shuffles only) --------------------
    {
        const int row0 = w * RPT;
        float acc[RPT][J];
#pragma unroll
        for (int r = 0; r < RPT; ++r)
#pragma unroll
            for (int j = 0; j < J; ++j) acc[r][j] = 0.f;

        const float* ekb = ek + bh * (64 * LK) + lane;

#pragma unroll
        for (int j = 0; j < J; ++j) {
            if (64 * j < valid) {             // wave-uniform skip
#pragma unroll
                for (int hc = 0; hc < 16; ++hc) {
                    const float4 wv4 = *(const float4*)(wv + hc * 4);   // uniform
                    float wva[4] = {wv4.x, wv4.y, wv4.z, wv4.w};
                    float eqa[RPT][4];
#pragma unroll
                    for (int r = 0; r < RPT; ++r) {
                        const float4 q4 = *(const float4*)(eq_lds + (row0 + r) * 64 + hc * 4);
                        eqa[r][0] = q4.x; eqa[r][1] = q4.y;
                        eqa[r][2] = q4.z; eqa[r][3] = q4.w;
                    }
#pragma unroll
                    for (int hp = 0; hp < 2; ++hp) {
                        const float ek0 = ekb[(hc * 4 + 2 * hp    ) * LK + 64 * j];
                        const float ek1 = ekb[(hc * 4 + 2 * hp + 1) * LK + 64 * j];
#pragma unroll
                        for (int r = 0; r < RPT; ++r) {
                            const float da = fmaf(eqa[r][2 * hp    ], ek0, 1.0f);
                            const float db = fmaf(eqa[r][2 * hp + 1], ek1, 1.0f);
                            float n = wva[2 * hp] * db;
                            n = fmaf(wva[2 * hp + 1], da, n);
                            acc[r][j] = fmaf(n, fast_rcp(da * db), acc[r][j]);
                        }
                    }
                }
            }
        }

#pragma unroll
        for (int r = 0; r < RPT; ++r) {
            float sv[J];
            float m = -3.0e38f;
#pragma unroll
            for (int j = 0; j < J; ++j) {
                sv[j] = (64 * j + lane < valid) ? acc[r][j] * NEGS : -1.0e6f;
                m = fmaxf(m, sv[j]);
            }
#pragma unroll
            for (int off = 1; off < 64; off <<= 1) m = fmaxf(m, __shfl_xor(m, off));
            float lsum = 0.f;
#pragma unroll
            for (int j = 0; j < J; ++j) { sv[j] = fast_exp2(sv[j] - m); lsum += sv[j]; }
#pragma unroll
            for (int off = 1; off < 64; off <<= 1) lsum += __shfl_xor(lsum, off);
            const float inv = fast_rcp(lsum);
#pragma unroll
            for (int j = 0; j < J; ++j)
                P_lds[(row0 + r) * LK + 64 * j + lane] = sv[j] * inv;
        }
    }
    __syncthreads();

    // ---- PV: thread = (d=t&31, kc=t>>5); V in reg chunks of 8 ------------
    {
        const int d = t & 31, kc = t >> 5;
        float acc2[TQ];
#pragma unroll
        for (int row = 0; row < TQ; ++row) acc2[row] = 0.f;

        if (kc * CS < valid) {
            const float* vp = v + (b * LK + kc * CS) * 256 + hd * 32 + d;
#pragma unroll
            for (int c = 0; c < CS / 8; ++c) {
                float vv[8];
#pragma unroll
                for (int i = 0; i < 8; ++i) vv[i] = vp[(c * 8 + i) * 256];
#pragma unroll
                for (int row = 0; row < TQ; ++row) {
                    const float4* pp = (const float4*)(P_lds + row * LK + kc * CS + c * 8);
                    const float4 p0 = pp[0], p1 = pp[1];
                    acc2[row] += p0.x * vv[0] + p0.y * vv[1] + p0.z * vv[2] + p0.w * vv[3]
                               + p1.x * vv[4] + p1.y * vv[5] + p1.z * vv[6] + p1.w * vv[7];
                }
            }
        }
#pragma unroll
        for (int row = 0; row < TQ; ++row)
            pv_lds[(kc * TQ + row) * 32 + d] = acc2[row];
    }
    __syncthreads();

    // ---- cross-kc reduce + write merged-head layout ----------------------
#pragma unroll
    for (int rr = 0; rr < (TQ * 32) / 256; ++rr) {
        const int idx = t + 256 * rr;
        const int dd = idx & 31, row = idx >> 5;
        float o = 0.f;
#pragma unroll
        for (int kc2 = 0; kc2 < 8; ++kc2) o += pv_lds[(kc2 * TQ + row) * 32 + dd];
        ho[(b * LQ + q0 + row) * 256 + hd * 32 + dd] = o;
    }
}

__global__ __launch_bounds__(256, 6) void k2_attn(
    const float* __restrict__ ql, const float* __restrict__ qr,
    const float* __restrict__ wql, const float* __restrict__ wqr,
    const float* __restrict__ ekl, const float* __restrict__ ekr,
    const float* __restrict__ wvl, const float* __restrict__ wvr,
    const float* __restrict__ vr, const float* __restrict__ vl,
    const int* __restrict__ vlr, const int* __restrict__ vll,
    float* __restrict__ hol, float* __restrict__ hor)
{
    __shared__ __align__(16) float P_lds[2048];    // 8 KB (8x256 / 16x128)
    __shared__ __align__(16) float pv_lds[4096];   // 16 KB
    __shared__ __align__(16) float eq_lds[1024];   // 4 KB (TQ x 64, max TQ=16)
    int blk = blockIdx.x;
    if (blk < 512) {            // left: LK=256, LQ=128, TQ=8
        const int bh = blk >> 4, q0 = (blk & 15) << 3;
        attn_fused<256, 128, 8>(bh, q0, ql, wql, ekl, wvl, vr, vlr[bh >> 3],
                                hol, P_lds, pv_lds, eq_lds);
    } else {                    // right: LK=128, LQ=256, TQ=16
        blk -= 512;
        const int bh = blk >> 4, q0 = (blk & 15) << 4;
        attn_fused<128, 256, 16>(bh, q0, qr, wqr, ekr, wvr, vl, vll[bh >> 3],
                                 hor, P_lds, pv_lds, eq_lds);
    }
}

// ---------------------------------------------------------------------------
// K3: output projections.  4 rows/block -> 384 blocks.
// ---------------------------------------------------------------------------
__global__ __launch_bounds__(256) void k3_proj(
    const float* __restrict__ ws,
    const float* __restrict__ wol, const float* __restrict__ wor,
    float* __restrict__ out)
{
    __shared__ __align__(16) float a_lds[1024];
    const int row0 = blockIdx.x * 4;
    const float* A; const float* W; float* op; int lr0;
    if (row0 < 512) { A = ws + OFF_HOL; W = wol; op = out;          lr0 = row0; }
    else            { A = ws + OFF_HOR; W = wor; op = out + 131072; lr0 = row0 - 512; }

    const int t = threadIdx.x;
#pragma unroll
    for (int i = 0; i < 4; ++i) a_lds[i * 256 + t] = A[(lr0 + i) * 256 + t];
    __syncthreads();

    float acc[4];
#pragma unroll
    for (int r = 0; r < 4; ++r) acc[r] = 0.f;

#pragma unroll 4
    for (int k4 = 0; k4 < 64; ++k4) {
        const float w0 = W[(k4 * 4 + 0) * 256 + t];
        const float w1 = W[(k4 * 4 + 1) * 256 + t];
        const float w2 = W[(k4 * 4 + 2) * 256 + t];
        const float w3 = W[(k4 * 4 + 3) * 256 + t];
#pragma unroll
        for (int r = 0; r < 4; ++r) {
            const float4 a = *(const float4*)(a_lds + r * 256 + k4 * 4);
            acc[r] += a.x * w0 + a.y * w1 + a.z * w2 + a.w * w3;
        }
    }
#pragma unroll
    for (int r = 0; r < 4; ++r) op[(lr0 + r) * 256 + t] = acc[r];
}

// ---------------------------------------------------------------------------
extern "C" void kernel_launch(void* const* d_in, const int* in_sizes, int n_in,
                              void* d_out, int out_size, void* d_ws, size_t ws_size,
                              hipStream_t stream)
{
    const float* ql  = (const float*)d_in[0];
    const float* kr  = (const float*)d_in[1];
    const float* vr  = (const float*)d_in[2];
    const float* qr  = (const float*)d_in[3];
    const float* kl  = (const float*)d_in[4];
    const float* vl  = (const float*)d_in[5];
    const float* wql = (const float*)d_in[6];
    const float* wkl = (const float*)d_in[7];
    const float* wvl = (const float*)d_in[8];
    const float* wol = (const float*)d_in[9];
    const float* wqr = (const float*)d_in[10];
    const float* wkr = (const float*)d_in[11];
    const float* wvr = (const float*)d_in[12];
    const float* wor = (const float*)d_in[13];
    const int*   vlr = (const int*)d_in[14];
    const int*   vll = (const int*)d_in[15];
    float* ws  = (float*)d_ws;
    float* out = (float*)d_out;

    hipLaunchKernelGGL(k1_proj, dim3(768), dim3(256), 0, stream,
                       kr, kl, wkl, wkr, ws);
    hipLaunchKernelGGL(k2_attn, dim3(1024), dim3(256), 0, stream,
                       ql, qr, wql, wqr, ws + OFF_EKL, ws + OFF_EKR,
                       wvl, wvr, vr, vl, vlr, vll,
                       ws + OFF_HOL, ws + OFF_HOR);
    hipLaunchKernelGGL(k3_proj, dim3(384), dim3(256), 0, stream,
                       ws, wol, wor, out);
}